// Round 1
// baseline (332.588 us; speedup 1.0000x reference)
//
#include <hip/hip_runtime.h>

typedef unsigned short ushort_t;

#define B_SZ 8192
#define D_SZ 1024
#define U_SZ 512
#define F_SZ 4
#define E_SZ 4
#define T_SZ 2

typedef __attribute__((ext_vector_type(8))) short bf16x8;     // 8 bf16 = 4 VGPRs (MFMA A/B frag)
typedef __attribute__((ext_vector_type(4))) float f32x4;      // MFMA C/D frag
typedef __attribute__((ext_vector_type(8))) unsigned short u16x8;

__device__ __forceinline__ unsigned short f2bf(float f) {
  union { float f; unsigned int u; } v; v.f = f;
  unsigned int r = v.u + 0x7FFFu + ((v.u >> 16) & 1u);  // RNE; inputs are finite normals
  return (unsigned short)(r >> 16);
}
__device__ __forceinline__ float bf2f(unsigned short h) {
  union { unsigned int u; float f; } v; v.u = ((unsigned int)h) << 16;
  return v.f;
}

// async global->LDS, 16B per lane; LDS dest = wave-uniform base + lane*16
__device__ __forceinline__ void gload_lds16(const void* g, void* l) {
  __builtin_amdgcn_global_load_lds(
      (const __attribute__((address_space(1))) unsigned int*)g,
      (__attribute__((address_space(3))) unsigned int*)l, 16, 0, 0);
}

// ---------------- convert x (fp32 -> bf16) ----------------
__global__ __launch_bounds__(256) void conv_x(const float* __restrict__ x,
                                              ushort_t* __restrict__ xbf) {
  const size_t i = ((size_t)blockIdx.x * 256 + threadIdx.x) * 8;
  const float4 a = *(const float4*)(x + i);
  const float4 c = *(const float4*)(x + i + 4);
  u16x8 o;
  o[0] = f2bf(a.x); o[1] = f2bf(a.y); o[2] = f2bf(a.z); o[3] = f2bf(a.w);
  o[4] = f2bf(c.x); o[5] = f2bf(c.y); o[6] = f2bf(c.z); o[7] = f2bf(c.w);
  *(u16x8*)(xbf + i) = o;
}

// ------- transpose + convert weights: 17 matrices [D][U] fp32 -> [U][D] bf16 -------
// matrix 0 = Wc, matrices 1..16 = We[f][e]
__global__ __launch_bounds__(256) void conv_w(const float* __restrict__ Wc,
                                              const float* __restrict__ We,
                                              ushort_t* __restrict__ wbf) {
  const int blk = blockIdx.x;
  const int midx = blk >> 9;            // /512 tiles per matrix
  const int tid = blk & 511;
  const int trow = (tid >> 4) * 32;     // d tile origin (32 of them)
  const int tcol = (tid & 15) * 32;     // u tile origin (16 of them)
  const float* src = (midx == 0) ? Wc : (We + (size_t)(midx - 1) * D_SZ * U_SZ);
  ushort_t* dst = wbf + (size_t)midx * U_SZ * D_SZ;
  __shared__ float tile[32][33];
  const int c = threadIdx.x & 31;
  const int r = threadIdx.x >> 5;       // 0..7
#pragma unroll
  for (int k = 0; k < 4; ++k)
    tile[r + k * 8][c] = src[(size_t)(trow + r + k * 8) * U_SZ + tcol + c];
  __syncthreads();
#pragma unroll
  for (int k = 0; k < 4; ++k) {
    const int rr = r + k * 8;
    dst[(size_t)(tcol + rr) * D_SZ + trow + c] = f2bf(tile[c][rr]);
  }
}

// ---------------- per-row expert masks (exact fp32 comparisons) ----------------
__global__ __launch_bounds__(256) void mask_k(const float* __restrict__ x,
                                              float* __restrict__ mask) {
  const int b = blockIdx.x * 256 + threadIdx.x;
  const float* xr = x + (size_t)b * D_SZ;
  float m[16];
#pragma unroll
  for (int f = 0; f < 2; ++f)
#pragma unroll
    for (int j = 0; j < 4; ++j)
      m[f * 4 + j] = (xr[f * 4 + j] > 0.f) ? 1.f : 0.f;
  const float LO[4] = {-1e10f, -0.5f, 0.f, 0.5f};
  const float HI[4] = {-0.5f, 0.f, 0.5f, 1e10f};
#pragma unroll
  for (int f = 0; f < 2; ++f) {
    const float v = xr[8 + f];
#pragma unroll
    for (int j = 0; j < 4; ++j)
      m[8 + f * 4 + j] = ((v > LO[j]) && (v <= HI[j])) ? 1.f : 0.f;
  }
#pragma unroll
  for (int k = 0; k < 4; ++k) {
    float4 v4 = {m[k * 4], m[k * 4 + 1], m[k * 4 + 2], m[k * 4 + 3]};
    *(float4*)(mask + (size_t)b * 16 + k * 4) = v4;
  }
}

// ---------------- gate softmax: gates[b][10] (t-major, 5 per task) ----------------
__global__ __launch_bounds__(256) void gates_k(const float* __restrict__ x,
                                               const float* __restrict__ Wg,
                                               const float* __restrict__ bg,
                                               float* __restrict__ gates) {
  const int t = threadIdx.x;
  const int lane = t & 63;
  const int w = t >> 6;
  const int b = blockIdx.x * 4 + w;     // one wave per row
  const float* xr = x + (size_t)b * D_SZ;
  float p[10];
#pragma unroll
  for (int j = 0; j < 10; ++j) p[j] = 0.f;
#pragma unroll
  for (int i = 0; i < 4; ++i) {
    const int d0 = i * 256 + lane * 4;
    const float4 xv = *(const float4*)(xr + d0);
#pragma unroll
    for (int t2 = 0; t2 < 2; ++t2) {
      const float* wg = Wg + t2 * (D_SZ * 5) + d0 * 5;  // Wg[t2][d][g]
#pragma unroll
      for (int g = 0; g < 5; ++g)
        p[t2 * 5 + g] += xv.x * wg[g] + xv.y * wg[5 + g] + xv.z * wg[10 + g] + xv.w * wg[15 + g];
    }
  }
#pragma unroll
  for (int off = 32; off > 0; off >>= 1)
#pragma unroll
    for (int j = 0; j < 10; ++j) p[j] += __shfl_xor(p[j], off);
  float l[10];
#pragma unroll
  for (int j = 0; j < 10; ++j) l[j] = p[j] + bg[j];
  const float mx0 = fmaxf(fmaxf(fmaxf(l[0], l[1]), fmaxf(l[2], l[3])), l[4]);
  const float mx1 = fmaxf(fmaxf(fmaxf(l[5], l[6]), fmaxf(l[7], l[8])), l[9]);
  float ev[10]; float s0 = 0.f, s1 = 0.f;
#pragma unroll
  for (int g = 0; g < 5; ++g) { ev[g] = expf(l[g] - mx0); s0 += ev[g]; }
#pragma unroll
  for (int g = 5; g < 10; ++g) { ev[g] = expf(l[g] - mx1); s1 += ev[g]; }
  if (lane < 5) gates[(size_t)b * 10 + lane] = ev[lane] / s0;
  else if (lane < 10) gates[(size_t)b * 10 + lane] = ev[lane] / s1;
}

// ---------------- fused bf16 MFMA GEMM ----------------
// grid.x = B/128 (m-tiles); grid.y = 20: 0..15 -> (f = y/4, uchunk = y%4) field groups
// (loops E=4 experts, mask+relu reduce -> field_out), 16..19 -> common u-chunks (relu -> common).
// LDS A/B tiles 128x64 bf16, 16B-chunk XOR swizzle (chunk' = chunk ^ (row&7)) so
// global_load_lds stays contiguous-in-lane while ds_read_b128 frags are <=2-way conflicted.
__global__ __launch_bounds__(256, 2) void gemm_fused(
    const ushort_t* __restrict__ xbf, const ushort_t* __restrict__ wbf,
    const float* __restrict__ mask, const float* __restrict__ bc,
    const float* __restrict__ be,
    ushort_t* __restrict__ common, ushort_t* __restrict__ fout) {
  __shared__ ushort_t Ash[128 * 64];
  __shared__ ushort_t Bsh[128 * 64];
  __shared__ float mk[128 * 4];

  const int t = threadIdx.x;
  const int lane = t & 63;
  const int w = t >> 6;          // wave 0..3, 2x2 wave grid, 64x64 per wave
  const int wm = w >> 1;
  const int wn = w & 1;
  const int quad = lane >> 4;
  const int l16 = lane & 15;
  const int m0 = blockIdx.x * 128;
  const int grp = blockIdx.y;
  const bool isCommon = grp >= 16;
  const int f = isCommon ? 0 : (grp >> 2);
  const int uc = isCommon ? (grp - 16) : (grp & 3);
  const int u0 = uc * 128;
  const int nExp = isCommon ? 1 : 4;
  const int midx0 = isCommon ? 0 : (1 + f * 4);

  if (!isCommon && t < 128)
    *(float4*)(&mk[t * 4]) = *(const float4*)(mask + (size_t)(m0 + t) * 16 + f * 4);

  // staging: 1024 16B-chunks per tile; thread's 4 issues; same (row,chunk) map for A and B
  int offs[4];
#pragma unroll
  for (int i = 0; i < 4; ++i) {
    const int c = (w * 4 + i) * 64 + lane;
    const int r = c >> 3;                    // tile row 0..127
    const int gc = (c & 7) ^ (r & 7);        // global chunk for this LDS slot (XOR swizzle)
    offs[i] = r * D_SZ + gc * 8;             // element offset within [128 x D] panel
  }
  const ushort_t* xbase = xbf + (size_t)m0 * D_SZ;

  int rowA[4], rowB[4];
#pragma unroll
  for (int i = 0; i < 4; ++i) {
    rowA[i] = wm * 64 + i * 16 + l16;
    rowB[i] = wn * 64 + i * 16 + l16;
  }
  // swizzled chunk offset within a row depends only on (qs,quad,l16&7): rows differ by mult of 8
  int sw[2];
  sw[0] = ((quad) ^ (l16 & 7)) * 8;
  sw[1] = ((4 + quad) ^ (l16 & 7)) * 8;

  const f32x4 fzero = {0.f, 0.f, 0.f, 0.f};
  f32x4 facc[4][4];
#pragma unroll
  for (int mi = 0; mi < 4; ++mi)
#pragma unroll
    for (int ni = 0; ni < 4; ++ni) facc[mi][ni] = fzero;

  for (int e = 0; e < nExp; ++e) {
    const ushort_t* wbase = wbf + (size_t)(midx0 + e) * (U_SZ * D_SZ) + (size_t)u0 * D_SZ;
    f32x4 acc[4][4];
#pragma unroll
    for (int mi = 0; mi < 4; ++mi)
#pragma unroll
      for (int ni = 0; ni < 4; ++ni) acc[mi][ni] = fzero;

    for (int k0 = 0; k0 < D_SZ; k0 += 64) {
#pragma unroll
      for (int i = 0; i < 4; ++i) {
        gload_lds16(xbase + offs[i] + k0, (char*)Ash + (w * 4 + i) * 1024);
        gload_lds16(wbase + offs[i] + k0, (char*)Bsh + (w * 4 + i) * 1024);
      }
      __syncthreads();   // compiler emits vmcnt(0) drain before barrier
#pragma unroll
      for (int qs = 0; qs < 2; ++qs) {
        bf16x8 av[4], bv[4];
#pragma unroll
        for (int mi = 0; mi < 4; ++mi)
          av[mi] = *(const bf16x8*)(Ash + rowA[mi] * 64 + sw[qs]);
#pragma unroll
        for (int ni = 0; ni < 4; ++ni)
          bv[ni] = *(const bf16x8*)(Bsh + rowB[ni] * 64 + sw[qs]);
#pragma unroll
        for (int mi = 0; mi < 4; ++mi)
#pragma unroll
          for (int ni = 0; ni < 4; ++ni)
            acc[mi][ni] = __builtin_amdgcn_mfma_f32_16x16x32_bf16(av[mi], bv[ni],
                                                                  acc[mi][ni], 0, 0, 0);
      }
      __syncthreads();
    }

    if (isCommon) {
#pragma unroll
      for (int mi = 0; mi < 4; ++mi) {
        const int rowb = m0 + wm * 64 + mi * 16 + quad * 4;   // C/D row = quad*4 + reg
#pragma unroll
        for (int ni = 0; ni < 4; ++ni) {
          const int u = u0 + wn * 64 + ni * 16 + l16;          // C/D col = lane&15
          const float bcv = bc[u];
#pragma unroll
          for (int r = 0; r < 4; ++r) {
            const float v = fmaxf(acc[mi][ni][r] + bcv, 0.f);
            common[(size_t)(rowb + r) * U_SZ + u] = f2bf(v);
          }
        }
      }
    } else {
#pragma unroll
      for (int ni = 0; ni < 4; ++ni) {
        const int u = u0 + wn * 64 + ni * 16 + l16;
        const float bev = be[(f * 4 + e) * U_SZ + u];
#pragma unroll
        for (int mi = 0; mi < 4; ++mi) {
          const int rowl = wm * 64 + mi * 16 + quad * 4;
#pragma unroll
          for (int r = 0; r < 4; ++r) {
            const float mval = mk[(rowl + r) * 4 + e];
            const float v = fmaxf(acc[mi][ni][r] + bev, 0.f);
            facc[mi][ni][r] += mval * v;
          }
        }
      }
    }
  }

  if (!isCommon) {
#pragma unroll
    for (int mi = 0; mi < 4; ++mi) {
      const int rowl = wm * 64 + mi * 16 + quad * 4;
#pragma unroll
      for (int ni = 0; ni < 4; ++ni) {
        const int u = u0 + wn * 64 + ni * 16 + l16;
#pragma unroll
        for (int r = 0; r < 4; ++r)
          fout[((size_t)(m0 + rowl + r) * F_SZ + f) * U_SZ + u] = f2bf(facc[mi][ni][r]);
      }
    }
  }
}

// ---------------- stage 2: att/upd scalars, blend, gate mix ----------------
__global__ __launch_bounds__(256) void stage2_k(
    const ushort_t* __restrict__ common, const ushort_t* __restrict__ fout,
    const float* __restrict__ gates,
    const float* __restrict__ Wa, const float* __restrict__ ba,
    const float* __restrict__ Wu, const float* __restrict__ bu,
    float* __restrict__ out) {
  const int b = blockIdx.x;
  const int t = threadIdx.x;
  const int lane = t & 63;
  const int w = t >> 6;

  const float c0 = bf2f(common[(size_t)b * U_SZ + t]);
  const float c1 = bf2f(common[(size_t)b * U_SZ + 256 + t]);
  float fo0[4], fo1[4];
#pragma unroll
  for (int f = 0; f < 4; ++f) {
    fo0[f] = bf2f(fout[((size_t)b * F_SZ + f) * U_SZ + t]);
    fo1[f] = bf2f(fout[((size_t)b * F_SZ + f) * U_SZ + 256 + t]);
  }
  float pa[4], pu[4];
#pragma unroll
  for (int f = 0; f < 4; ++f) {
    const float* wa = Wa + f * 1024;   // cat = [common(0..511), field(512..1023)]
    pa[f] = c0 * wa[t] + c1 * wa[256 + t] + fo0[f] * wa[512 + t] + fo1[f] * wa[768 + t];
    const float* wu = Wu + f * 1024;
    pu[f] = c0 * wu[t] + c1 * wu[256 + t] + fo0[f] * wu[512 + t] + fo1[f] * wu[768 + t];
  }
#pragma unroll
  for (int off = 32; off > 0; off >>= 1) {
#pragma unroll
    for (int f = 0; f < 4; ++f) {
      pa[f] += __shfl_xor(pa[f], off);
      pu[f] += __shfl_xor(pu[f], off);
    }
  }
  __shared__ float redA[4][4];
  __shared__ float redU[4][4];
  __shared__ float gsh[10];
  if (lane == 0) {
#pragma unroll
    for (int f = 0; f < 4; ++f) { redA[w][f] = pa[f]; redU[w][f] = pu[f]; }
  }
  if (t < 10) gsh[t] = gates[(size_t)b * 10 + t];
  __syncthreads();
  float att[4], upd[4], ff0[4], ff1[4];
#pragma unroll
  for (int f = 0; f < 4; ++f) {
    const float sa = redA[0][f] + redA[1][f] + redA[2][f] + redA[3][f] + ba[f];
    const float su = redU[0][f] + redU[1][f] + redU[2][f] + redU[3][f] + bu[f];
    att[f] = 1.f / (1.f + expf(-sa));
    upd[f] = 1.f / (1.f + expf(-su));
    ff0[f] = upd[f] * (att[f] * fo0[f]) + (1.f - upd[f]) * c0;
    ff1[f] = upd[f] * (att[f] * fo1[f]) + (1.f - upd[f]) * c1;
  }
#pragma unroll
  for (int t2 = 0; t2 < 2; ++t2) {
    float v0 = gsh[t2 * 5] * c0;
    float v1 = gsh[t2 * 5] * c1;
#pragma unroll
    for (int f = 0; f < 4; ++f) {
      v0 += gsh[t2 * 5 + 1 + f] * ff0[f];
      v1 += gsh[t2 * 5 + 1 + f] * ff1[f];
    }
    out[((size_t)b * T_SZ + t2) * U_SZ + t] = v0;
    out[((size_t)b * T_SZ + t2) * U_SZ + 256 + t] = v1;
  }
}

// ---------------- launch ----------------
extern "C" void kernel_launch(void* const* d_in, const int* in_sizes, int n_in,
                              void* d_out, int out_size, void* d_ws, size_t ws_size,
                              hipStream_t stream) {
  (void)in_sizes; (void)n_in; (void)out_size; (void)ws_size;
  const float* x  = (const float*)d_in[0];
  const float* Wc = (const float*)d_in[1];
  const float* bc = (const float*)d_in[2];
  const float* We = (const float*)d_in[3];
  const float* be = (const float*)d_in[4];
  const float* Wg = (const float*)d_in[5];
  const float* bg = (const float*)d_in[6];
  const float* Wa = (const float*)d_in[7];
  const float* ba = (const float*)d_in[8];
  const float* Wu = (const float*)d_in[9];
  const float* bu = (const float*)d_in[10];
  float* out = (float*)d_out;
  char* ws = (char*)d_ws;

  // ws layout (bytes), all 16B aligned; total ~77.4 MB
  const size_t O_XBF    = 0;                               // B*D*2       = 16,777,216
  const size_t O_WBF    = O_XBF + (size_t)B_SZ * D_SZ * 2; // 17*U*D*2    = 17,825,792
  const size_t O_MASK   = O_WBF + (size_t)17 * U_SZ * D_SZ * 2;   // B*16*4 = 524,288
  const size_t O_GATES  = O_MASK + (size_t)B_SZ * 16 * 4;         // B*10*4 = 327,680
  const size_t O_COMMON = O_GATES + (size_t)B_SZ * 10 * 4;        // B*U*2  = 8,388,608
  const size_t O_FOUT   = O_COMMON + (size_t)B_SZ * U_SZ * 2;     // B*F*U*2 = 33,554,432

  ushort_t* xbf    = (ushort_t*)(ws + O_XBF);
  ushort_t* wbf    = (ushort_t*)(ws + O_WBF);
  float*    maskp  = (float*)(ws + O_MASK);
  float*    gatesp = (float*)(ws + O_GATES);
  ushort_t* commonp= (ushort_t*)(ws + O_COMMON);
  ushort_t* foutp  = (ushort_t*)(ws + O_FOUT);

  conv_x<<<dim3(4096), dim3(256), 0, stream>>>(x, xbf);
  conv_w<<<dim3(17 * 512), dim3(256), 0, stream>>>(Wc, We, wbf);
  mask_k<<<dim3(32), dim3(256), 0, stream>>>(x, maskp);
  gates_k<<<dim3(2048), dim3(256), 0, stream>>>(x, Wg, bg, gatesp);
  gemm_fused<<<dim3(64, 20), dim3(256), 0, stream>>>(xbf, wbf, maskp, bc, be, commonp, foutp);
  stage2_k<<<dim3(8192), dim3(256), 0, stream>>>(commonp, foutp, gatesp, Wa, ba, Wu, bu, out);
}

// Round 2
// 328.442 us; speedup vs baseline: 1.0126x; 1.0126x over previous
//
#include <hip/hip_runtime.h>

typedef unsigned short ushort_t;

#define B_SZ 8192
#define D_SZ 1024
#define U_SZ 512
#define F_SZ 4
#define E_SZ 4
#define T_SZ 2

typedef __attribute__((ext_vector_type(8))) short bf16x8;     // 8 bf16 = 4 VGPRs (MFMA A/B frag)
typedef __attribute__((ext_vector_type(4))) float f32x4;      // MFMA C/D frag
typedef __attribute__((ext_vector_type(8))) unsigned short u16x8;

__device__ __forceinline__ unsigned short f2bf(float f) {
  union { float f; unsigned int u; } v; v.f = f;
  unsigned int r = v.u + 0x7FFFu + ((v.u >> 16) & 1u);  // RNE; inputs are finite normals
  return (unsigned short)(r >> 16);
}
__device__ __forceinline__ float bf2f(unsigned short h) {
  union { unsigned int u; float f; } v; v.u = ((unsigned int)h) << 16;
  return v.f;
}

// async global->LDS, 16B per lane; LDS dest = wave-uniform base + lane*16
__device__ __forceinline__ void gload_lds16(const void* g, void* l) {
  __builtin_amdgcn_global_load_lds(
      (const __attribute__((address_space(1))) unsigned int*)g,
      (__attribute__((address_space(3))) unsigned int*)l, 16, 0, 0);
}

// ---------------- convert x (fp32 -> bf16) + fused per-row expert masks ----------------
// block = 256 threads * 8 elem = 2048 elem = exactly 2 rows of x.
// Threads 0 and 128 own elements 0..7 of their row -> they compute the row's masks.
__global__ __launch_bounds__(256) void conv_x(const float* __restrict__ x,
                                              ushort_t* __restrict__ xbf,
                                              float* __restrict__ mask) {
  const size_t i = ((size_t)blockIdx.x * 256 + threadIdx.x) * 8;
  const float4 a = *(const float4*)(x + i);
  const float4 c = *(const float4*)(x + i + 4);
  u16x8 o;
  o[0] = f2bf(a.x); o[1] = f2bf(a.y); o[2] = f2bf(a.z); o[3] = f2bf(a.w);
  o[4] = f2bf(c.x); o[5] = f2bf(c.y); o[6] = f2bf(c.z); o[7] = f2bf(c.w);
  *(u16x8*)(xbf + i) = o;

  if ((threadIdx.x & 127) == 0) {
    const int b = blockIdx.x * 2 + (threadIdx.x >> 7);
    const float* xr = x + (size_t)b * D_SZ;     // a = xr[0..3], c = xr[4..7]
    float m[16];
    m[0] = a.x > 0.f ? 1.f : 0.f; m[1] = a.y > 0.f ? 1.f : 0.f;
    m[2] = a.z > 0.f ? 1.f : 0.f; m[3] = a.w > 0.f ? 1.f : 0.f;
    m[4] = c.x > 0.f ? 1.f : 0.f; m[5] = c.y > 0.f ? 1.f : 0.f;
    m[6] = c.z > 0.f ? 1.f : 0.f; m[7] = c.w > 0.f ? 1.f : 0.f;
    const float LO[4] = {-1e10f, -0.5f, 0.f, 0.5f};
    const float HI[4] = {-0.5f, 0.f, 0.5f, 1e10f};
    const float v0 = xr[8], v1 = xr[9];
#pragma unroll
    for (int j = 0; j < 4; ++j) {
      m[8 + j]  = ((v0 > LO[j]) && (v0 <= HI[j])) ? 1.f : 0.f;
      m[12 + j] = ((v1 > LO[j]) && (v1 <= HI[j])) ? 1.f : 0.f;
    }
#pragma unroll
    for (int k = 0; k < 4; ++k) {
      float4 v4 = {m[k * 4], m[k * 4 + 1], m[k * 4 + 2], m[k * 4 + 3]};
      *(float4*)(mask + (size_t)b * 16 + k * 4) = v4;
    }
  }
}

// ------- transpose + convert weights: 17 matrices [D][U] fp32 -> [U][D] bf16 -------
// 64x64 tiles: float4 global reads, u16x8 (16B) global writes, LDS pad 69 (2-way max).
__global__ __launch_bounds__(256) void conv_w(const float* __restrict__ Wc,
                                              const float* __restrict__ We,
                                              ushort_t* __restrict__ wbf) {
  const int blk = blockIdx.x;
  const int midx = blk >> 7;            // 128 tiles per matrix (16 d-tiles x 8 u-tiles)
  const int tid = blk & 127;
  const int trow = (tid >> 3) * 64;     // d origin
  const int tcol = (tid & 7) * 64;      // u origin
  const float* src = (midx == 0) ? Wc : (We + (size_t)(midx - 1) * D_SZ * U_SZ);
  ushort_t* dst = wbf + (size_t)midx * U_SZ * D_SZ;

  __shared__ float tile[64][69];
  const int t = threadIdx.x;
  const int r0 = t >> 2;                // 0..63 (d row within tile)
  const int cseg = (t & 3) * 16;        // 16 floats per thread along u
#pragma unroll
  for (int j = 0; j < 4; ++j) {
    const float4 v = *(const float4*)(src + (size_t)(trow + r0) * U_SZ + tcol + cseg + j * 4);
    tile[r0][cseg + j * 4 + 0] = v.x;
    tile[r0][cseg + j * 4 + 1] = v.y;
    tile[r0][cseg + j * 4 + 2] = v.z;
    tile[r0][cseg + j * 4 + 3] = v.w;
  }
  __syncthreads();
  const int u = t >> 2;                 // 0..63 (u row of output)
  const int d0 = (t & 3) * 16;          // 16 d per thread -> two 16B stores
#pragma unroll
  for (int h = 0; h < 2; ++h) {
    u16x8 ov;
#pragma unroll
    for (int k = 0; k < 8; ++k) ov[k] = f2bf(tile[d0 + h * 8 + k][u]);
    *(u16x8*)(dst + (size_t)(tcol + u) * D_SZ + trow + d0 + h * 8) = ov;
  }
}

// ---------------- gate softmax: gates[b][10] ----------------
// Wg staged transposed into LDS once per block; all global reads coalesced float4,
// all LDS reads contiguous-b128 (conflict-free). 8 rows/block (2 per wave).
__global__ __launch_bounds__(256) void gates_k(const float* __restrict__ x,
                                               const float* __restrict__ Wg,
                                               const float* __restrict__ bg,
                                               float* __restrict__ gates) {
  __shared__ float wgT[10 * 1024];
  const int t = threadIdx.x;
#pragma unroll
  for (int j = 0; j < 40; ++j) {
    const int i = j * 256 + t;          // coalesced read of Wg[t2][d][g]
    const int t2 = i / 5120;
    const int rem = i - t2 * 5120;
    const int d = rem / 5;
    const int g = rem - d * 5;
    wgT[(t2 * 5 + g) * 1024 + d] = Wg[i];
  }
  __syncthreads();
  const int lane = t & 63;
  const int w = t >> 6;
#pragma unroll
  for (int rr = 0; rr < 2; ++rr) {
    const int b = blockIdx.x * 8 + w * 2 + rr;
    const float* xr = x + (size_t)b * D_SZ;
    float p[10];
#pragma unroll
    for (int j = 0; j < 10; ++j) p[j] = 0.f;
#pragma unroll
    for (int i = 0; i < 4; ++i) {
      const int d0 = i * 256 + lane * 4;
      const float4 xv = *(const float4*)(xr + d0);
#pragma unroll
      for (int g = 0; g < 10; ++g) {
        const float4 wv = *(const float4*)(wgT + g * 1024 + d0);
        p[g] += xv.x * wv.x + xv.y * wv.y + xv.z * wv.z + xv.w * wv.w;
      }
    }
#pragma unroll
    for (int off = 32; off > 0; off >>= 1)
#pragma unroll
      for (int j = 0; j < 10; ++j) p[j] += __shfl_xor(p[j], off);
    float l[10];
#pragma unroll
    for (int j = 0; j < 10; ++j) l[j] = p[j] + bg[j];
    const float mx0 = fmaxf(fmaxf(fmaxf(l[0], l[1]), fmaxf(l[2], l[3])), l[4]);
    const float mx1 = fmaxf(fmaxf(fmaxf(l[5], l[6]), fmaxf(l[7], l[8])), l[9]);
    float ev[10]; float s0 = 0.f, s1 = 0.f;
#pragma unroll
    for (int g = 0; g < 5; ++g) { ev[g] = expf(l[g] - mx0); s0 += ev[g]; }
#pragma unroll
    for (int g = 5; g < 10; ++g) { ev[g] = expf(l[g] - mx1); s1 += ev[g]; }
    if (lane < 5) gates[(size_t)b * 10 + lane] = ev[lane] / s0;
    else if (lane < 10) gates[(size_t)b * 10 + lane] = ev[lane] / s1;
  }
}

// ---------------- fused bf16 MFMA GEMM ----------------
// grid.x = B/128 (m-tiles); grid.y = 20: 0..15 -> (f = y/4, uchunk = y%4) field groups
// (loops E=4 experts, mask+relu reduce -> field_out), 16..19 -> common u-chunks (relu -> common).
// LDS A/B tiles 128x64 bf16, 16B-chunk XOR swizzle (chunk' = chunk ^ (row&7)) so
// global_load_lds stays contiguous-in-lane while ds_read_b128 frags are <=2-way conflicted.
__global__ __launch_bounds__(256, 2) void gemm_fused(
    const ushort_t* __restrict__ xbf, const ushort_t* __restrict__ wbf,
    const float* __restrict__ mask, const float* __restrict__ bc,
    const float* __restrict__ be,
    ushort_t* __restrict__ common, ushort_t* __restrict__ fout) {
  __shared__ ushort_t Ash[128 * 64];
  __shared__ ushort_t Bsh[128 * 64];
  __shared__ float mk[128 * 4];

  const int t = threadIdx.x;
  const int lane = t & 63;
  const int w = t >> 6;          // wave 0..3, 2x2 wave grid, 64x64 per wave
  const int wm = w >> 1;
  const int wn = w & 1;
  const int quad = lane >> 4;
  const int l16 = lane & 15;
  const int m0 = blockIdx.x * 128;
  const int grp = blockIdx.y;
  const bool isCommon = grp >= 16;
  const int f = isCommon ? 0 : (grp >> 2);
  const int uc = isCommon ? (grp - 16) : (grp & 3);
  const int u0 = uc * 128;
  const int nExp = isCommon ? 1 : 4;
  const int midx0 = isCommon ? 0 : (1 + f * 4);

  if (!isCommon && t < 128)
    *(float4*)(&mk[t * 4]) = *(const float4*)(mask + (size_t)(m0 + t) * 16 + f * 4);

  // staging: 1024 16B-chunks per tile; thread's 4 issues; same (row,chunk) map for A and B
  int offs[4];
#pragma unroll
  for (int i = 0; i < 4; ++i) {
    const int c = (w * 4 + i) * 64 + lane;
    const int r = c >> 3;                    // tile row 0..127
    const int gc = (c & 7) ^ (r & 7);        // global chunk for this LDS slot (XOR swizzle)
    offs[i] = r * D_SZ + gc * 8;             // element offset within [128 x D] panel
  }
  const ushort_t* xbase = xbf + (size_t)m0 * D_SZ;

  int rowA[4], rowB[4];
#pragma unroll
  for (int i = 0; i < 4; ++i) {
    rowA[i] = wm * 64 + i * 16 + l16;
    rowB[i] = wn * 64 + i * 16 + l16;
  }
  // swizzled chunk offset within a row depends only on (qs,quad,l16&7): rows differ by mult of 8
  int sw[2];
  sw[0] = ((quad) ^ (l16 & 7)) * 8;
  sw[1] = ((4 + quad) ^ (l16 & 7)) * 8;

  const f32x4 fzero = {0.f, 0.f, 0.f, 0.f};
  f32x4 facc[4][4];
#pragma unroll
  for (int mi = 0; mi < 4; ++mi)
#pragma unroll
    for (int ni = 0; ni < 4; ++ni) facc[mi][ni] = fzero;

  for (int e = 0; e < nExp; ++e) {
    const ushort_t* wbase = wbf + (size_t)(midx0 + e) * (U_SZ * D_SZ) + (size_t)u0 * D_SZ;
    f32x4 acc[4][4];
#pragma unroll
    for (int mi = 0; mi < 4; ++mi)
#pragma unroll
      for (int ni = 0; ni < 4; ++ni) acc[mi][ni] = fzero;

    for (int k0 = 0; k0 < D_SZ; k0 += 64) {
#pragma unroll
      for (int i = 0; i < 4; ++i) {
        gload_lds16(xbase + offs[i] + k0, (char*)Ash + (w * 4 + i) * 1024);
        gload_lds16(wbase + offs[i] + k0, (char*)Bsh + (w * 4 + i) * 1024);
      }
      __syncthreads();   // compiler emits vmcnt(0) drain before barrier
#pragma unroll
      for (int qs = 0; qs < 2; ++qs) {
        bf16x8 av[4], bv[4];
#pragma unroll
        for (int mi = 0; mi < 4; ++mi)
          av[mi] = *(const bf16x8*)(Ash + rowA[mi] * 64 + sw[qs]);
#pragma unroll
        for (int ni = 0; ni < 4; ++ni)
          bv[ni] = *(const bf16x8*)(Bsh + rowB[ni] * 64 + sw[qs]);
#pragma unroll
        for (int mi = 0; mi < 4; ++mi)
#pragma unroll
          for (int ni = 0; ni < 4; ++ni)
            acc[mi][ni] = __builtin_amdgcn_mfma_f32_16x16x32_bf16(av[mi], bv[ni],
                                                                  acc[mi][ni], 0, 0, 0);
      }
      __syncthreads();
    }

    if (isCommon) {
#pragma unroll
      for (int mi = 0; mi < 4; ++mi) {
        const int rowb = m0 + wm * 64 + mi * 16 + quad * 4;   // C/D row = quad*4 + reg
#pragma unroll
        for (int ni = 0; ni < 4; ++ni) {
          const int u = u0 + wn * 64 + ni * 16 + l16;          // C/D col = lane&15
          const float bcv = bc[u];
#pragma unroll
          for (int r = 0; r < 4; ++r) {
            const float v = fmaxf(acc[mi][ni][r] + bcv, 0.f);
            common[(size_t)(rowb + r) * U_SZ + u] = f2bf(v);
          }
        }
      }
    } else {
#pragma unroll
      for (int ni = 0; ni < 4; ++ni) {
        const int u = u0 + wn * 64 + ni * 16 + l16;
        const float bev = be[(f * 4 + e) * U_SZ + u];
#pragma unroll
        for (int mi = 0; mi < 4; ++mi) {
          const int rowl = wm * 64 + mi * 16 + quad * 4;
#pragma unroll
          for (int r = 0; r < 4; ++r) {
            const float mval = mk[(rowl + r) * 4 + e];
            const float v = fmaxf(acc[mi][ni][r] + bev, 0.f);
            facc[mi][ni][r] += mval * v;
          }
        }
      }
    }
  }

  if (!isCommon) {
#pragma unroll
    for (int mi = 0; mi < 4; ++mi) {
      const int rowl = wm * 64 + mi * 16 + quad * 4;
#pragma unroll
      for (int ni = 0; ni < 4; ++ni) {
        const int u = u0 + wn * 64 + ni * 16 + l16;
#pragma unroll
        for (int r = 0; r < 4; ++r)
          fout[((size_t)(m0 + rowl + r) * F_SZ + f) * U_SZ + u] = f2bf(facc[mi][ni][r]);
      }
    }
  }
}

// ---------------- stage 2: att/upd scalars, blend, gate mix ----------------
__global__ __launch_bounds__(256) void stage2_k(
    const ushort_t* __restrict__ common, const ushort_t* __restrict__ fout,
    const float* __restrict__ gates,
    const float* __restrict__ Wa, const float* __restrict__ ba,
    const float* __restrict__ Wu, const float* __restrict__ bu,
    float* __restrict__ out) {
  const int b = blockIdx.x;
  const int t = threadIdx.x;
  const int lane = t & 63;
  const int w = t >> 6;

  const float c0 = bf2f(common[(size_t)b * U_SZ + t]);
  const float c1 = bf2f(common[(size_t)b * U_SZ + 256 + t]);
  float fo0[4], fo1[4];
#pragma unroll
  for (int f = 0; f < 4; ++f) {
    fo0[f] = bf2f(fout[((size_t)b * F_SZ + f) * U_SZ + t]);
    fo1[f] = bf2f(fout[((size_t)b * F_SZ + f) * U_SZ + 256 + t]);
  }
  float pa[4], pu[4];
#pragma unroll
  for (int f = 0; f < 4; ++f) {
    const float* wa = Wa + f * 1024;   // cat = [common(0..511), field(512..1023)]
    pa[f] = c0 * wa[t] + c1 * wa[256 + t] + fo0[f] * wa[512 + t] + fo1[f] * wa[768 + t];
    const float* wu = Wu + f * 1024;
    pu[f] = c0 * wu[t] + c1 * wu[256 + t] + fo0[f] * wu[512 + t] + fo1[f] * wu[768 + t];
  }
#pragma unroll
  for (int off = 32; off > 0; off >>= 1) {
#pragma unroll
    for (int f = 0; f < 4; ++f) {
      pa[f] += __shfl_xor(pa[f], off);
      pu[f] += __shfl_xor(pu[f], off);
    }
  }
  __shared__ float redA[4][4];
  __shared__ float redU[4][4];
  __shared__ float gsh[10];
  if (lane == 0) {
#pragma unroll
    for (int f = 0; f < 4; ++f) { redA[w][f] = pa[f]; redU[w][f] = pu[f]; }
  }
  if (t < 10) gsh[t] = gates[(size_t)b * 10 + t];
  __syncthreads();
  float att[4], upd[4], ff0[4], ff1[4];
#pragma unroll
  for (int f = 0; f < 4; ++f) {
    const float sa = redA[0][f] + redA[1][f] + redA[2][f] + redA[3][f] + ba[f];
    const float su = redU[0][f] + redU[1][f] + redU[2][f] + redU[3][f] + bu[f];
    att[f] = 1.f / (1.f + expf(-sa));
    upd[f] = 1.f / (1.f + expf(-su));
    ff0[f] = upd[f] * (att[f] * fo0[f]) + (1.f - upd[f]) * c0;
    ff1[f] = upd[f] * (att[f] * fo1[f]) + (1.f - upd[f]) * c1;
  }
#pragma unroll
  for (int t2 = 0; t2 < 2; ++t2) {
    float v0 = gsh[t2 * 5] * c0;
    float v1 = gsh[t2 * 5] * c1;
#pragma unroll
    for (int f = 0; f < 4; ++f) {
      v0 += gsh[t2 * 5 + 1 + f] * ff0[f];
      v1 += gsh[t2 * 5 + 1 + f] * ff1[f];
    }
    out[((size_t)b * T_SZ + t2) * U_SZ + t] = v0;
    out[((size_t)b * T_SZ + t2) * U_SZ + 256 + t] = v1;
  }
}

// ---------------- launch ----------------
extern "C" void kernel_launch(void* const* d_in, const int* in_sizes, int n_in,
                              void* d_out, int out_size, void* d_ws, size_t ws_size,
                              hipStream_t stream) {
  (void)in_sizes; (void)n_in; (void)out_size; (void)ws_size;
  const float* x  = (const float*)d_in[0];
  const float* Wc = (const float*)d_in[1];
  const float* bc = (const float*)d_in[2];
  const float* We = (const float*)d_in[3];
  const float* be = (const float*)d_in[4];
  const float* Wg = (const float*)d_in[5];
  const float* bg = (const float*)d_in[6];
  const float* Wa = (const float*)d_in[7];
  const float* ba = (const float*)d_in[8];
  const float* Wu = (const float*)d_in[9];
  const float* bu = (const float*)d_in[10];
  float* out = (float*)d_out;
  char* ws = (char*)d_ws;

  // ws layout (bytes), all 16B aligned; total ~77.4 MB
  const size_t O_XBF    = 0;                               // B*D*2       = 16,777,216
  const size_t O_WBF    = O_XBF + (size_t)B_SZ * D_SZ * 2; // 17*U*D*2    = 17,825,792
  const size_t O_MASK   = O_WBF + (size_t)17 * U_SZ * D_SZ * 2;   // B*16*4 = 524,288
  const size_t O_GATES  = O_MASK + (size_t)B_SZ * 16 * 4;         // B*10*4 = 327,680
  const size_t O_COMMON = O_GATES + (size_t)B_SZ * 10 * 4;        // B*U*2  = 8,388,608
  const size_t O_FOUT   = O_COMMON + (size_t)B_SZ * U_SZ * 2;     // B*F*U*2 = 33,554,432

  ushort_t* xbf    = (ushort_t*)(ws + O_XBF);
  ushort_t* wbf    = (ushort_t*)(ws + O_WBF);
  float*    maskp  = (float*)(ws + O_MASK);
  float*    gatesp = (float*)(ws + O_GATES);
  ushort_t* commonp= (ushort_t*)(ws + O_COMMON);
  ushort_t* foutp  = (ushort_t*)(ws + O_FOUT);

  conv_x<<<dim3(4096), dim3(256), 0, stream>>>(x, xbf, maskp);
  conv_w<<<dim3(17 * 128), dim3(256), 0, stream>>>(Wc, We, wbf);
  gates_k<<<dim3(1024), dim3(256), 0, stream>>>(x, Wg, bg, gatesp);
  gemm_fused<<<dim3(64, 20), dim3(256), 0, stream>>>(xbf, wbf, maskp, bc, be, commonp, foutp);
  stage2_k<<<dim3(8192), dim3(256), 0, stream>>>(commonp, foutp, gatesp, Wa, ba, Wu, bu, out);
}